// Round 4
// baseline (214.542 us; speedup 1.0000x reference)
//
#include <hip/hip_runtime.h>

#define NN 50000
#define NE 150000
#define NB 196  // ceil(NN/256)

// ---------- K1: degree histograms (self-loop handled as +1 at read) ----------
__global__ __launch_bounds__(256) void k_deg(const int* __restrict__ src,
                                             const int* __restrict__ dst,
                                             int* __restrict__ deg_out,
                                             int* __restrict__ deg_in) {
    int e = blockIdx.x * 256 + threadIdx.x;
    if (e < NE) {
        atomicAdd(&deg_out[src[e]], 1);
        atomicAdd(&deg_in[dst[e]], 1);
    }
}

// ---------- K2a: per-block partial sums of deg_in and deg_out ----------
__global__ __launch_bounds__(256) void k_bsum(const int* __restrict__ deg_in,
                                              const int* __restrict__ deg_out,
                                              int* __restrict__ bsum_in,
                                              int* __restrict__ bsum_out) {
    __shared__ int si[256], so[256];
    int t = threadIdx.x;
    int idx = blockIdx.x * 256 + t;
    si[t] = (idx < NN) ? deg_in[idx] : 0;
    so[t] = (idx < NN) ? deg_out[idx] : 0;
    __syncthreads();
    for (int off = 128; off >= 1; off >>= 1) {
        if (t < off) { si[t] += si[t + off]; so[t] += so[t + off]; }
        __syncthreads();
    }
    if (t == 0) { bsum_in[blockIdx.x] = si[0]; bsum_out[blockIdx.x] = so[0]; }
}

// ---------- K2b: rowptrs + precomputed norm tables + prescaled x ----------
__global__ __launch_bounds__(256) void k_rowptr(const int* __restrict__ deg_in,
                                                const int* __restrict__ deg_out,
                                                const int* __restrict__ bsum_in,
                                                const int* __restrict__ bsum_out,
                                                const float* __restrict__ x,
                                                int* __restrict__ rp_in,
                                                int* __restrict__ rp_out,
                                                float* __restrict__ dins,
                                                float* __restrict__ douts,
                                                float4* __restrict__ xs4) {
    __shared__ int si[256], so[256];
    int b = blockIdx.x, t = threadIdx.x;
    si[t] = (t < b) ? bsum_in[t] : 0;
    so[t] = (t < b) ? bsum_out[t] : 0;
    __syncthreads();
    for (int off = 128; off >= 1; off >>= 1) {
        if (t < off) { si[t] += si[t + off]; so[t] += so[t + off]; }
        __syncthreads();
    }
    int off_in = si[0], off_out = so[0];
    __syncthreads();
    int idx = b * 256 + t;
    int di = (idx < NN) ? deg_in[idx] : 0;
    int dq = (idx < NN) ? deg_out[idx] : 0;
    si[t] = di; so[t] = dq;
    __syncthreads();
    for (int off = 1; off < 256; off <<= 1) {
        int a = (t >= off) ? si[t - off] : 0;
        int c2 = (t >= off) ? so[t - off] : 0;
        __syncthreads();
        si[t] += a; so[t] += c2;
        __syncthreads();
    }
    if (idx < NN) {
        rp_in[idx]  = off_in  + si[t] - di;   // exclusive
        rp_out[idx] = off_out + so[t] - dq;
        float dif = rsqrtf((float)(di + 1));
        float dqf = rsqrtf((float)(dq + 1));
        dins[idx] = dif;
        douts[idx] = dqf;
        float4 x4 = ((const float4*)x)[idx];
        x4.x *= dqf; x4.y *= dqf; x4.z *= dqf; x4.w *= dqf;
        xs4[idx] = x4;
    }
    if (b == 0 && t == 0) { rp_in[NN] = NE; rp_out[NN] = NE; }
}

// ---------- K3: scatter edges; in-CSR stores {edge id, src} packed ----------
__global__ __launch_bounds__(256) void k_scatter(const int* __restrict__ src,
                                                 const int* __restrict__ dst,
                                                 const int* __restrict__ rp_in,
                                                 const int* __restrict__ rp_out,
                                                 int* __restrict__ cur_in,
                                                 int* __restrict__ cur_out,
                                                 int2* __restrict__ ei_pack,
                                                 int* __restrict__ nbr_out) {
    int e = blockIdx.x * 256 + threadIdx.x;
    if (e >= NE) return;
    int s = src[e], d = dst[e];
    int pi = rp_in[d] + atomicAdd(&cur_in[d], 1);
    ei_pack[pi] = make_int2(e, s);
    int po = rp_out[s] + atomicAdd(&cur_out[s], 1);
    nbr_out[po] = d;
}

// ---------- K4: conv1 via CSR gathers + fused 4->11 matvec/relu; c as store ----------
__global__ __launch_bounds__(256) void k_conv1g(const float4* __restrict__ xs4,
                                                const int2* __restrict__ ei_pack,
                                                const int* __restrict__ rp_in,
                                                const int* __restrict__ nbr_out,
                                                const int* __restrict__ rp_out,
                                                const float* __restrict__ dins,
                                                const float* __restrict__ douts,
                                                const float* __restrict__ W1,
                                                const float* __restrict__ b1,
                                                float* __restrict__ h1s,
                                                float* __restrict__ c) {
    int n = blockIdx.x * 256 + threadIdx.x;
    if (n >= NN) return;
    float din  = dins[n];
    float dout = douts[n];
    float4 a = xs4[n];  // self-loop term, pre-scaled by dout_n
    int beg = rp_in[n], end = rp_in[n + 1];
    for (int p = beg; p < end; p++) {
        int s = ei_pack[p].y;
        float4 xs = xs4[s];
        a.x += xs.x; a.y += xs.y; a.z += xs.z; a.w += xs.w;
    }
    float cacc = din;  // self loop
    int ob = rp_out[n], oe = rp_out[n + 1];
    for (int p = ob; p < oe; p++)
        cacc += dins[nbr_out[p]];
    c[n] = cacc;
    #pragma unroll
    for (int j = 0; j < 11; j++) {
        float y = a.x * W1[0 * 11 + j] + a.y * W1[1 * 11 + j] +
                  a.z * W1[2 * 11 + j] + a.w * W1[3 * 11 + j];
        y = fmaxf(fmaf(y, din, b1[j]), 0.f);
        h1s[n * 11 + j] = y * dout;
    }
}

// ---------- K5: FUSED conv2 gather + matvec + weighted mean-reduce into t[512] ----------
// block = 512 threads, 32 nodes. Phase1: 352 threads gather agg2 into LDS,
// 32 threads load din/w. Phase2: thread=channel, loop nodes, atomicAdd t.
#define G2 32
__global__ __launch_bounds__(512) void k_conv2f(const float* __restrict__ h1s,
                                                const float* __restrict__ ef,
                                                const int2* __restrict__ ei_pack,
                                                const int* __restrict__ rp_in,
                                                const float* __restrict__ c,
                                                const float* __restrict__ dins,
                                                const float* __restrict__ douts,
                                                const float* __restrict__ W2,
                                                const float* __restrict__ b2,
                                                float* __restrict__ t) {
    __shared__ float tile[G2 * 11];
    __shared__ float din_sh[G2], w_sh[G2];
    int n0 = blockIdx.x * G2;
    int tid = threadIdx.x;
    if (tid < G2 * 11) {
        int i = tid / 11, j = tid % 11;
        int n = n0 + i;
        float acc = 0.f;
        if (n < NN) {
            int beg = rp_in[n], end = rp_in[n + 1];
            for (int p = beg; p < end; p++) {
                int2 es = ei_pack[p];
                acc = fmaf(h1s[es.y * 11 + j], ef[es.x * 11 + j], acc);
            }
        }
        tile[tid] = acc;
    } else if (tid >= 512 - G2) {
        int i = tid - (512 - G2);
        int n = n0 + i;
        if (n < NN) {
            din_sh[i] = dins[n];
            w_sh[i]   = c[n] * douts[n] * (1.0f / NN);
        } else { din_sh[i] = 0.f; w_sh[i] = 0.f; }
    }
    __syncthreads();
    float w[11];
    #pragma unroll
    for (int j = 0; j < 11; j++) w[j] = W2[j * 512 + tid];
    float bias = b2[tid];
    float acc = 0.f;
    for (int i = 0; i < G2; i++) {
        float dot = 0.f;
        #pragma unroll
        for (int j = 0; j < 11; j++) dot = fmaf(tile[i * 11 + j], w[j], dot);
        float y = fmaxf(fmaf(dot, din_sh[i], bias), 0.f);
        acc = fmaf(w_sh[i], y, acc);
    }
    atomicAdd(&t[tid], acc);
}

// ---------- K6: g = t @ W3 + b3  (512x1024 matvec, k-split 32 ways) ----------
__global__ __launch_bounds__(256) void k_g(const float* __restrict__ t,
                                           const float* __restrict__ W3,
                                           const float* __restrict__ b3,
                                           float* __restrict__ g) {
    int b = blockIdx.x;          // 128 = 4 oc x 32 kc
    int oc = b & 3, kc = b >> 2;
    int o = oc * 256 + threadIdx.x;
    int k0 = kc * 16;
    __shared__ float ts[16];
    if (threadIdx.x < 16) ts[threadIdx.x] = t[k0 + threadIdx.x];
    __syncthreads();
    float acc = (kc == 0) ? b3[o] : 0.f;
    #pragma unroll
    for (int k = 0; k < 16; k++) acc = fmaf(ts[k], W3[(size_t)(k0 + k) * 1024 + o], acc);
    atomicAdd(&g[o], acc);
}

// ---------- K7: head layer-1 partial matvecs (bias/relu deferred) ----------
// grid 512 = oc(16) x kc(32); outputs 0..2047 -> hv_raw, 2048..4095 -> ha_raw
__global__ __launch_bounds__(256) void k_heads1(const float* __restrict__ g,
                                                const float* __restrict__ Wv1,
                                                const float* __restrict__ Wa1,
                                                float* __restrict__ hv_raw,
                                                float* __restrict__ ha_raw) {
    int b = blockIdx.x;
    int oc = b >> 5, kc = b & 31;
    int idx = oc * 256 + threadIdx.x;  // 0..4095
    int k0 = kc * 32;
    __shared__ float gs[32];
    if (threadIdx.x < 32) gs[threadIdx.x] = g[k0 + threadIdx.x];
    __syncthreads();
    const float* W; float* outp; int o;
    if (idx < 2048) { W = Wv1; outp = hv_raw; o = idx; }
    else            { W = Wa1; outp = ha_raw; o = idx - 2048; }
    float acc = 0.f;
    #pragma unroll 8
    for (int k = 0; k < 32; k++) acc = fmaf(gs[k], W[(size_t)(k0 + k) * 2048 + o], acc);
    atomicAdd(&outp[o], acc);
}

// ---------- K8: head layer-2: a partials (256 blocks) + v (1 block) ----------
__global__ __launch_bounds__(256) void k_heads2(const float* __restrict__ hv_raw,
                                                const float* __restrict__ bv1,
                                                const float* __restrict__ ha_raw,
                                                const float* __restrict__ ba1,
                                                const float* __restrict__ Wv2,
                                                const float* __restrict__ bv2,
                                                const float* __restrict__ Wa2,
                                                float* __restrict__ a_acc,
                                                float* __restrict__ v) {
    int b = blockIdx.x;
    int tid = threadIdx.x;
    if (b < 256) {
        int oc = b >> 6, kc = b & 63;   // oc 0..3, kc 0..63
        int k0 = kc * 32;
        __shared__ float hs[32];
        if (tid < 32) hs[tid] = fmaxf(ha_raw[k0 + tid] + ba1[k0 + tid], 0.f);
        __syncthreads();
        int o = oc * 256 + tid;  // 0..1023
        if (o < 1000) {
            float acc = 0.f;
            #pragma unroll 8
            for (int k = 0; k < 32; k++)
                acc = fmaf(hs[k], Wa2[(size_t)(k0 + k) * 1000 + o], acc);
            atomicAdd(&a_acc[o], acc);
        }
    } else {
        __shared__ float red[256];
        float acc = 0.f;
        for (int k = tid; k < 2048; k += 256)
            acc = fmaf(fmaxf(hv_raw[k] + bv1[k], 0.f), Wv2[k], acc);
        red[tid] = acc;
        __syncthreads();
        for (int s = 128; s >= 1; s >>= 1) {
            if (tid < s) red[tid] += red[tid + s];
            __syncthreads();
        }
        if (tid == 0) *v = red[0] + bv2[0];
    }
}

// ---------- K9: final: out = v + (a - mean(a)) ----------
__global__ __launch_bounds__(1024) void k_final(const float* __restrict__ a_acc,
                                                const float* __restrict__ ba2,
                                                const float* __restrict__ vptr,
                                                float* __restrict__ out) {
    __shared__ float red[1024];
    int tid = threadIdx.x;
    float ai = (tid < 1000) ? a_acc[tid] + ba2[tid] : 0.f;
    red[tid] = ai;
    __syncthreads();
    for (int s = 512; s >= 1; s >>= 1) {
        if (tid < s) red[tid] += red[tid + s];
        __syncthreads();
    }
    float amean = red[0] * (1.0f / 1000.0f);
    if (tid < 1000) out[tid] = vptr[0] + ai - amean;
}

extern "C" void kernel_launch(void* const* d_in, const int* in_sizes, int n_in,
                              void* d_out, int out_size, void* d_ws, size_t ws_size,
                              hipStream_t stream) {
    const float* x   = (const float*)d_in[0];
    const float* ef  = (const float*)d_in[1];
    const float* W1  = (const float*)d_in[2];
    const float* b1  = (const float*)d_in[3];
    const float* W2  = (const float*)d_in[4];
    const float* b2  = (const float*)d_in[5];
    const float* W3  = (const float*)d_in[6];
    const float* b3  = (const float*)d_in[7];
    const float* Wv1 = (const float*)d_in[8];
    const float* bv1 = (const float*)d_in[9];
    const float* Wv2 = (const float*)d_in[10];
    const float* bv2 = (const float*)d_in[11];
    const float* Wa1 = (const float*)d_in[12];
    const float* ba1 = (const float*)d_in[13];
    const float* Wa2 = (const float*)d_in[14];
    const float* ba2 = (const float*)d_in[15];
    const int*   src = (const int*)d_in[16];
    const int*   dst = (const int*)d_in[17];
    float* out = (float*)d_out;

    char* ws = (char*)d_ws;
    size_t off = 0;
    auto alloc = [&](size_t bytes) -> void* {
        void* p = ws + off;
        off = (off + bytes + 255) & ~(size_t)255;
        return p;
    };
    // --- zeroed region (accumulators) ---
    int*   deg_out = (int*)  alloc(NN * 4);
    int*   deg_in  = (int*)  alloc(NN * 4);
    int*   cur_in  = (int*)  alloc(NN * 4);
    int*   cur_out = (int*)  alloc(NN * 4);
    float* t       = (float*)alloc(512 * 4);
    float* g       = (float*)alloc(1024 * 4);
    float* hv_raw  = (float*)alloc(2048 * 4);
    float* ha_raw  = (float*)alloc(2048 * 4);
    float* a_acc   = (float*)alloc(1024 * 4);
    size_t zero_bytes = off;
    // --- non-zeroed scratch ---
    int*    bsum_in  = (int*)   alloc(NB * 4);
    int*    bsum_out = (int*)   alloc(NB * 4);
    int*    rp_in    = (int*)   alloc((NN + 1) * 4);
    int*    rp_out   = (int*)   alloc((NN + 1) * 4);
    float*  dins     = (float*) alloc(NN * 4);
    float*  douts    = (float*) alloc(NN * 4);
    float4* xs4      = (float4*)alloc((size_t)NN * 16);
    int2*   ei_pack  = (int2*)  alloc((size_t)NE * 8);
    int*    nbr_out  = (int*)   alloc((size_t)NE * 4);
    float*  c        = (float*) alloc(NN * 4);
    float*  h1s      = (float*) alloc((size_t)NN * 11 * 4);
    float*  v        = (float*) alloc(256);

    hipMemsetAsync(d_ws, 0, zero_bytes, stream);

    k_deg<<<(NE + 255) / 256, 256, 0, stream>>>(src, dst, deg_out, deg_in);
    k_bsum<<<NB, 256, 0, stream>>>(deg_in, deg_out, bsum_in, bsum_out);
    k_rowptr<<<NB, 256, 0, stream>>>(deg_in, deg_out, bsum_in, bsum_out, x,
                                     rp_in, rp_out, dins, douts, xs4);
    k_scatter<<<(NE + 255) / 256, 256, 0, stream>>>(src, dst, rp_in, rp_out,
                                                    cur_in, cur_out, ei_pack, nbr_out);
    k_conv1g<<<(NN + 255) / 256, 256, 0, stream>>>(xs4, ei_pack, rp_in, nbr_out, rp_out,
                                                   dins, douts, W1, b1, h1s, c);
    k_conv2f<<<(NN + G2 - 1) / G2, 512, 0, stream>>>(h1s, ef, ei_pack, rp_in, c,
                                                     dins, douts, W2, b2, t);
    k_g<<<128, 256, 0, stream>>>(t, W3, b3, g);
    k_heads1<<<512, 256, 0, stream>>>(g, Wv1, Wa1, hv_raw, ha_raw);
    k_heads2<<<257, 256, 0, stream>>>(hv_raw, bv1, ha_raw, ba1, Wv2, bv2, Wa2, a_acc, v);
    k_final<<<1, 1024, 0, stream>>>(a_acc, ba2, v, out);
}

// Round 5
// 210.371 us; speedup vs baseline: 1.0198x; 1.0198x over previous
//
#include <hip/hip_runtime.h>

#define NN 50000
#define NE 150000
#define NB 196  // ceil(NN/256)

// ---------- K1: degree histograms (self-loop handled as +1 at read) ----------
__global__ __launch_bounds__(256) void k_deg(const int* __restrict__ src,
                                             const int* __restrict__ dst,
                                             int* __restrict__ deg_out,
                                             int* __restrict__ deg_in) {
    int e = blockIdx.x * 256 + threadIdx.x;
    if (e < NE) {
        atomicAdd(&deg_out[src[e]], 1);
        atomicAdd(&deg_in[dst[e]], 1);
    }
}

// ---------- K2a: per-block partial sums of deg_in and deg_out ----------
__global__ __launch_bounds__(256) void k_bsum(const int* __restrict__ deg_in,
                                              const int* __restrict__ deg_out,
                                              int* __restrict__ bsum_in,
                                              int* __restrict__ bsum_out) {
    __shared__ int si[256], so[256];
    int t = threadIdx.x;
    int idx = blockIdx.x * 256 + t;
    si[t] = (idx < NN) ? deg_in[idx] : 0;
    so[t] = (idx < NN) ? deg_out[idx] : 0;
    __syncthreads();
    for (int off = 128; off >= 1; off >>= 1) {
        if (t < off) { si[t] += si[t + off]; so[t] += so[t + off]; }
        __syncthreads();
    }
    if (t == 0) { bsum_in[blockIdx.x] = si[0]; bsum_out[blockIdx.x] = so[0]; }
}

// ---------- K2b: rowptrs + precomputed norm tables + prescaled x ----------
__global__ __launch_bounds__(256) void k_rowptr(const int* __restrict__ deg_in,
                                                const int* __restrict__ deg_out,
                                                const int* __restrict__ bsum_in,
                                                const int* __restrict__ bsum_out,
                                                const float* __restrict__ x,
                                                int* __restrict__ rp_in,
                                                int* __restrict__ rp_out,
                                                float* __restrict__ dins,
                                                float* __restrict__ douts,
                                                float4* __restrict__ xs4) {
    __shared__ int si[256], so[256];
    int b = blockIdx.x, t = threadIdx.x;
    si[t] = (t < b) ? bsum_in[t] : 0;
    so[t] = (t < b) ? bsum_out[t] : 0;
    __syncthreads();
    for (int off = 128; off >= 1; off >>= 1) {
        if (t < off) { si[t] += si[t + off]; so[t] += so[t + off]; }
        __syncthreads();
    }
    int off_in = si[0], off_out = so[0];
    __syncthreads();
    int idx = b * 256 + t;
    int di = (idx < NN) ? deg_in[idx] : 0;
    int dq = (idx < NN) ? deg_out[idx] : 0;
    si[t] = di; so[t] = dq;
    __syncthreads();
    for (int off = 1; off < 256; off <<= 1) {
        int a = (t >= off) ? si[t - off] : 0;
        int c2 = (t >= off) ? so[t - off] : 0;
        __syncthreads();
        si[t] += a; so[t] += c2;
        __syncthreads();
    }
    if (idx < NN) {
        rp_in[idx]  = off_in  + si[t] - di;   // exclusive
        rp_out[idx] = off_out + so[t] - dq;
        float dif = rsqrtf((float)(di + 1));
        float dqf = rsqrtf((float)(dq + 1));
        dins[idx] = dif;
        douts[idx] = dqf;
        float4 x4 = ((const float4*)x)[idx];
        x4.x *= dqf; x4.y *= dqf; x4.z *= dqf; x4.w *= dqf;
        xs4[idx] = x4;
    }
    if (b == 0 && t == 0) { rp_in[NN] = NE; rp_out[NN] = NE; }
}

// ---------- K3: scatter edges into CSR; permute ef into CSR order (padded 12) ----------
__global__ __launch_bounds__(256) void k_scatter(const int* __restrict__ src,
                                                 const int* __restrict__ dst,
                                                 const float* __restrict__ ef,
                                                 const int* __restrict__ rp_in,
                                                 const int* __restrict__ rp_out,
                                                 int* __restrict__ cur_in,
                                                 int* __restrict__ cur_out,
                                                 int* __restrict__ nbr_in,
                                                 float4* __restrict__ ef4,
                                                 int* __restrict__ nbr_out) {
    int e = blockIdx.x * 256 + threadIdx.x;
    if (e >= NE) return;
    int s = src[e], d = dst[e];
    int pi = rp_in[d] + atomicAdd(&cur_in[d], 1);
    nbr_in[pi] = s;
    const float* er = ef + (size_t)e * 11;
    ef4[(size_t)pi * 3 + 0] = make_float4(er[0], er[1], er[2], er[3]);
    ef4[(size_t)pi * 3 + 1] = make_float4(er[4], er[5], er[6], er[7]);
    ef4[(size_t)pi * 3 + 2] = make_float4(er[8], er[9], er[10], 0.f);
    int po = rp_out[s] + atomicAdd(&cur_out[s], 1);
    nbr_out[po] = d;
}

// ---------- K4: conv1 via CSR gathers + fused 4->11 matvec/relu; h1s padded to 12 ----------
__global__ __launch_bounds__(256) void k_conv1g(const float4* __restrict__ xs4,
                                                const int* __restrict__ nbr_in,
                                                const int* __restrict__ rp_in,
                                                const int* __restrict__ nbr_out,
                                                const int* __restrict__ rp_out,
                                                const float* __restrict__ dins,
                                                const float* __restrict__ douts,
                                                const float* __restrict__ W1,
                                                const float* __restrict__ b1,
                                                float4* __restrict__ h1s4,
                                                float* __restrict__ c) {
    int n = blockIdx.x * 256 + threadIdx.x;
    if (n >= NN) return;
    float din  = dins[n];
    float dout = douts[n];
    float4 a = xs4[n];  // self-loop term, pre-scaled by dout_n
    int beg = rp_in[n], end = rp_in[n + 1];
    for (int p = beg; p < end; p++) {
        float4 xs = xs4[nbr_in[p]];
        a.x += xs.x; a.y += xs.y; a.z += xs.z; a.w += xs.w;
    }
    float cacc = din;  // self loop
    int ob = rp_out[n], oe = rp_out[n + 1];
    for (int p = ob; p < oe; p++)
        cacc += dins[nbr_out[p]];
    c[n] = cacc;
    float y[12];
    #pragma unroll
    for (int j = 0; j < 11; j++) {
        float t2 = a.x * W1[0 * 11 + j] + a.y * W1[1 * 11 + j] +
                   a.z * W1[2 * 11 + j] + a.w * W1[3 * 11 + j];
        y[j] = fmaxf(fmaf(t2, din, b1[j]), 0.f) * dout;
    }
    y[11] = 0.f;
    h1s4[(size_t)n * 3 + 0] = make_float4(y[0], y[1], y[2],  y[3]);
    h1s4[(size_t)n * 3 + 1] = make_float4(y[4], y[5], y[6],  y[7]);
    h1s4[(size_t)n * 3 + 2] = make_float4(y[8], y[9], y[10], y[11]);
}

// ---------- K5: conv2 — edge-slot-parallel gather into LDS, matvec + weighted reduce ----------
#define G2 64
__global__ __launch_bounds__(512) void k_conv2f(const float4* __restrict__ h1s4,
                                                const float4* __restrict__ ef4,
                                                const int* __restrict__ nbr_in,
                                                const int* __restrict__ rp_in,
                                                const float* __restrict__ c,
                                                const float* __restrict__ dins,
                                                const float* __restrict__ douts,
                                                const float* __restrict__ W2,
                                                const float* __restrict__ b2,
                                                float* __restrict__ t) {
    __shared__ float tile[G2 * 12];
    __shared__ int rp_sh[G2 + 1];
    __shared__ float din_sh[G2], w_sh[G2];
    int tid = threadIdx.x;
    int n0 = blockIdx.x * G2;
    if (tid <= G2) {
        int n = n0 + tid;
        rp_sh[tid] = rp_in[(n > NN) ? NN : n];
    }
    for (int i = tid; i < G2 * 12; i += 512) tile[i] = 0.f;
    if (tid < G2) {
        int n = n0 + tid;
        if (n < NN) { din_sh[tid] = dins[n]; w_sh[tid] = c[n] * douts[n] * (1.0f / NN); }
        else        { din_sh[tid] = 0.f;     w_sh[tid] = 0.f; }
    }
    __syncthreads();
    int pbeg = rp_sh[0], pend = rp_sh[G2];
    for (int p = pbeg + tid; p < pend; p += 512) {
        int s = nbr_in[p];
        float4 ha = h1s4[(size_t)s * 3 + 0];
        float4 hb = h1s4[(size_t)s * 3 + 1];
        float4 hc = h1s4[(size_t)s * 3 + 2];
        float4 ea = ef4[(size_t)p * 3 + 0];
        float4 eb = ef4[(size_t)p * 3 + 1];
        float4 ec = ef4[(size_t)p * 3 + 2];
        int lo = 0, hi = G2;
        while (hi - lo > 1) { int mid = (lo + hi) >> 1; if (rp_sh[mid] <= p) lo = mid; else hi = mid; }
        float* row = &tile[lo * 12];
        atomicAdd(&row[0],  ha.x * ea.x);
        atomicAdd(&row[1],  ha.y * ea.y);
        atomicAdd(&row[2],  ha.z * ea.z);
        atomicAdd(&row[3],  ha.w * ea.w);
        atomicAdd(&row[4],  hb.x * eb.x);
        atomicAdd(&row[5],  hb.y * eb.y);
        atomicAdd(&row[6],  hb.z * eb.z);
        atomicAdd(&row[7],  hb.w * eb.w);
        atomicAdd(&row[8],  hc.x * ec.x);
        atomicAdd(&row[9],  hc.y * ec.y);
        atomicAdd(&row[10], hc.z * ec.z);
    }
    __syncthreads();
    float w[11];
    #pragma unroll
    for (int j = 0; j < 11; j++) w[j] = W2[j * 512 + tid];
    float bias = b2[tid];
    float acc = 0.f;
    for (int i = 0; i < G2; i++) {
        const float4* trow = (const float4*)&tile[i * 12];
        float4 ta = trow[0], tb = trow[1], tc = trow[2];
        float dot = ta.x * w[0] + ta.y * w[1] + ta.z * w[2] + ta.w * w[3] +
                    tb.x * w[4] + tb.y * w[5] + tb.z * w[6] + tb.w * w[7] +
                    tc.x * w[8] + tc.y * w[9] + tc.z * w[10];
        float y = fmaxf(fmaf(dot, din_sh[i], bias), 0.f);
        acc = fmaf(w_sh[i], y, acc);
    }
    atomicAdd(&t[tid], acc);
}

// ---------- K6: g = t @ W3 + b3  (512x1024 matvec, k-split 32 ways) ----------
__global__ __launch_bounds__(256) void k_g(const float* __restrict__ t,
                                           const float* __restrict__ W3,
                                           const float* __restrict__ b3,
                                           float* __restrict__ g) {
    int b = blockIdx.x;          // 128 = 4 oc x 32 kc
    int oc = b & 3, kc = b >> 2;
    int o = oc * 256 + threadIdx.x;
    int k0 = kc * 16;
    __shared__ float ts[16];
    if (threadIdx.x < 16) ts[threadIdx.x] = t[k0 + threadIdx.x];
    __syncthreads();
    float acc = (kc == 0) ? b3[o] : 0.f;
    #pragma unroll
    for (int k = 0; k < 16; k++) acc = fmaf(ts[k], W3[(size_t)(k0 + k) * 1024 + o], acc);
    atomicAdd(&g[o], acc);
}

// ---------- K7: head layer-1 partial matvecs (bias/relu deferred) ----------
// grid 512 = oc(16) x kc(32); outputs 0..2047 -> hv_raw, 2048..4095 -> ha_raw
__global__ __launch_bounds__(256) void k_heads1(const float* __restrict__ g,
                                                const float* __restrict__ Wv1,
                                                const float* __restrict__ Wa1,
                                                float* __restrict__ hv_raw,
                                                float* __restrict__ ha_raw) {
    int b = blockIdx.x;
    int oc = b >> 5, kc = b & 31;
    int idx = oc * 256 + threadIdx.x;  // 0..4095
    int k0 = kc * 32;
    __shared__ float gs[32];
    if (threadIdx.x < 32) gs[threadIdx.x] = g[k0 + threadIdx.x];
    __syncthreads();
    const float* W; float* outp; int o;
    if (idx < 2048) { W = Wv1; outp = hv_raw; o = idx; }
    else            { W = Wa1; outp = ha_raw; o = idx - 2048; }
    float acc = 0.f;
    #pragma unroll 8
    for (int k = 0; k < 32; k++) acc = fmaf(gs[k], W[(size_t)(k0 + k) * 2048 + o], acc);
    atomicAdd(&outp[o], acc);
}

// ---------- K8: head layer-2: a partials (256 blocks) + v (1 block) ----------
__global__ __launch_bounds__(256) void k_heads2(const float* __restrict__ hv_raw,
                                                const float* __restrict__ bv1,
                                                const float* __restrict__ ha_raw,
                                                const float* __restrict__ ba1,
                                                const float* __restrict__ Wv2,
                                                const float* __restrict__ bv2,
                                                const float* __restrict__ Wa2,
                                                float* __restrict__ a_acc,
                                                float* __restrict__ v) {
    int b = blockIdx.x;
    int tid = threadIdx.x;
    if (b < 256) {
        int oc = b >> 6, kc = b & 63;   // oc 0..3, kc 0..63
        int k0 = kc * 32;
        __shared__ float hs[32];
        if (tid < 32) hs[tid] = fmaxf(ha_raw[k0 + tid] + ba1[k0 + tid], 0.f);
        __syncthreads();
        int o = oc * 256 + tid;  // 0..1023
        if (o < 1000) {
            float acc = 0.f;
            #pragma unroll 8
            for (int k = 0; k < 32; k++)
                acc = fmaf(hs[k], Wa2[(size_t)(k0 + k) * 1000 + o], acc);
            atomicAdd(&a_acc[o], acc);
        }
    } else {
        __shared__ float red[256];
        float acc = 0.f;
        for (int k = tid; k < 2048; k += 256)
            acc = fmaf(fmaxf(hv_raw[k] + bv1[k], 0.f), Wv2[k], acc);
        red[tid] = acc;
        __syncthreads();
        for (int s = 128; s >= 1; s >>= 1) {
            if (tid < s) red[tid] += red[tid + s];
            __syncthreads();
        }
        if (tid == 0) *v = red[0] + bv2[0];
    }
}

// ---------- K9: final: out = v + (a - mean(a)) ----------
__global__ __launch_bounds__(1024) void k_final(const float* __restrict__ a_acc,
                                                const float* __restrict__ ba2,
                                                const float* __restrict__ vptr,
                                                float* __restrict__ out) {
    __shared__ float red[1024];
    int tid = threadIdx.x;
    float ai = (tid < 1000) ? a_acc[tid] + ba2[tid] : 0.f;
    red[tid] = ai;
    __syncthreads();
    for (int s = 512; s >= 1; s >>= 1) {
        if (tid < s) red[tid] += red[tid + s];
        __syncthreads();
    }
    float amean = red[0] * (1.0f / 1000.0f);
    if (tid < 1000) out[tid] = vptr[0] + ai - amean;
}

extern "C" void kernel_launch(void* const* d_in, const int* in_sizes, int n_in,
                              void* d_out, int out_size, void* d_ws, size_t ws_size,
                              hipStream_t stream) {
    const float* x   = (const float*)d_in[0];
    const float* ef  = (const float*)d_in[1];
    const float* W1  = (const float*)d_in[2];
    const float* b1  = (const float*)d_in[3];
    const float* W2  = (const float*)d_in[4];
    const float* b2  = (const float*)d_in[5];
    const float* W3  = (const float*)d_in[6];
    const float* b3  = (const float*)d_in[7];
    const float* Wv1 = (const float*)d_in[8];
    const float* bv1 = (const float*)d_in[9];
    const float* Wv2 = (const float*)d_in[10];
    const float* bv2 = (const float*)d_in[11];
    const float* Wa1 = (const float*)d_in[12];
    const float* ba1 = (const float*)d_in[13];
    const float* Wa2 = (const float*)d_in[14];
    const float* ba2 = (const float*)d_in[15];
    const int*   src = (const int*)d_in[16];
    const int*   dst = (const int*)d_in[17];
    float* out = (float*)d_out;

    char* ws = (char*)d_ws;
    size_t off = 0;
    auto alloc = [&](size_t bytes) -> void* {
        void* p = ws + off;
        off = (off + bytes + 255) & ~(size_t)255;
        return p;
    };
    // --- zeroed region (accumulators) ---
    int*   deg_out = (int*)  alloc(NN * 4);
    int*   deg_in  = (int*)  alloc(NN * 4);
    int*   cur_in  = (int*)  alloc(NN * 4);
    int*   cur_out = (int*)  alloc(NN * 4);
    float* t       = (float*)alloc(512 * 4);
    float* g       = (float*)alloc(1024 * 4);
    float* hv_raw  = (float*)alloc(2048 * 4);
    float* ha_raw  = (float*)alloc(2048 * 4);
    float* a_acc   = (float*)alloc(1024 * 4);
    size_t zero_bytes = off;
    // --- non-zeroed scratch ---
    int*    bsum_in  = (int*)   alloc(NB * 4);
    int*    bsum_out = (int*)   alloc(NB * 4);
    int*    rp_in    = (int*)   alloc((NN + 1) * 4);
    int*    rp_out   = (int*)   alloc((NN + 1) * 4);
    float*  dins     = (float*) alloc(NN * 4);
    float*  douts    = (float*) alloc(NN * 4);
    float4* xs4      = (float4*)alloc((size_t)NN * 16);
    int*    nbr_in   = (int*)   alloc((size_t)NE * 4);
    int*    nbr_out  = (int*)   alloc((size_t)NE * 4);
    float4* ef4      = (float4*)alloc((size_t)NE * 48);
    float4* h1s4     = (float4*)alloc((size_t)NN * 48);
    float*  c        = (float*) alloc(NN * 4);
    float*  v        = (float*) alloc(256);

    hipMemsetAsync(d_ws, 0, zero_bytes, stream);

    k_deg<<<(NE + 255) / 256, 256, 0, stream>>>(src, dst, deg_out, deg_in);
    k_bsum<<<NB, 256, 0, stream>>>(deg_in, deg_out, bsum_in, bsum_out);
    k_rowptr<<<NB, 256, 0, stream>>>(deg_in, deg_out, bsum_in, bsum_out, x,
                                     rp_in, rp_out, dins, douts, xs4);
    k_scatter<<<(NE + 255) / 256, 256, 0, stream>>>(src, dst, ef, rp_in, rp_out,
                                                    cur_in, cur_out, nbr_in, ef4, nbr_out);
    k_conv1g<<<(NN + 255) / 256, 256, 0, stream>>>(xs4, nbr_in, rp_in, nbr_out, rp_out,
                                                   dins, douts, W1, b1, h1s4, c);
    k_conv2f<<<(NN + G2 - 1) / G2, 512, 0, stream>>>(h1s4, ef4, nbr_in, rp_in, c,
                                                     dins, douts, W2, b2, t);
    k_g<<<128, 256, 0, stream>>>(t, W3, b3, g);
    k_heads1<<<512, 256, 0, stream>>>(g, Wv1, Wa1, hv_raw, ha_raw);
    k_heads2<<<257, 256, 0, stream>>>(hv_raw, bv1, ha_raw, ba1, Wv2, bv2, Wa2, a_acc, v);
    k_final<<<1, 1024, 0, stream>>>(a_acc, ba2, v, out);
}

// Round 6
// 209.554 us; speedup vs baseline: 1.0238x; 1.0039x over previous
//
#include <hip/hip_runtime.h>

#define NN 50000
#define NE 150000
#define NB 196  // ceil(NN/256)

// ---------- K1: degree histograms (self-loop handled as +1 at read) ----------
__global__ __launch_bounds__(256) void k_deg(const int* __restrict__ src,
                                             const int* __restrict__ dst,
                                             int* __restrict__ deg_out,
                                             int* __restrict__ deg_in) {
    int e = blockIdx.x * 256 + threadIdx.x;
    if (e < NE) {
        atomicAdd(&deg_out[src[e]], 1);
        atomicAdd(&deg_in[dst[e]], 1);
    }
}

// ---------- K2a: per-block partial sums of deg_in ----------
__global__ __launch_bounds__(256) void k_bsum(const int* __restrict__ deg_in,
                                              int* __restrict__ bsum_in) {
    __shared__ int si[256];
    int t = threadIdx.x;
    int idx = blockIdx.x * 256 + t;
    si[t] = (idx < NN) ? deg_in[idx] : 0;
    __syncthreads();
    for (int off = 128; off >= 1; off >>= 1) {
        if (t < off) si[t] += si[t + off];
        __syncthreads();
    }
    if (t == 0) bsum_in[blockIdx.x] = si[0];
}

// ---------- K2b: rowptr (in) + precomputed norm tables + prescaled x ----------
__global__ __launch_bounds__(256) void k_rowptr(const int* __restrict__ deg_in,
                                                const int* __restrict__ deg_out,
                                                const int* __restrict__ bsum_in,
                                                const float* __restrict__ x,
                                                int* __restrict__ rp_in,
                                                float* __restrict__ dins,
                                                float* __restrict__ douts,
                                                float4* __restrict__ xs4) {
    __shared__ int si[256];
    int b = blockIdx.x, t = threadIdx.x;
    si[t] = (t < b) ? bsum_in[t] : 0;
    __syncthreads();
    for (int off = 128; off >= 1; off >>= 1) {
        if (t < off) si[t] += si[t + off];
        __syncthreads();
    }
    int off_in = si[0];
    __syncthreads();
    int idx = b * 256 + t;
    int di = (idx < NN) ? deg_in[idx] : 0;
    si[t] = di;
    __syncthreads();
    for (int off = 1; off < 256; off <<= 1) {
        int a = (t >= off) ? si[t - off] : 0;
        __syncthreads();
        si[t] += a;
        __syncthreads();
    }
    if (idx < NN) {
        rp_in[idx] = off_in + si[t] - di;   // exclusive
        float dif = rsqrtf((float)(di + 1));
        float dqf = rsqrtf((float)(deg_out[idx] + 1));
        dins[idx] = dif;
        douts[idx] = dqf;
        float4 x4 = ((const float4*)x)[idx];
        x4.x *= dqf; x4.y *= dqf; x4.z *= dqf; x4.w *= dqf;
        xs4[idx] = x4;
    }
    if (b == 0 && t == 0) rp_in[NN] = NE;
}

// ---------- K3: scatter edges into dst-CSR {src,dst}, permute ef, accumulate c ----------
__global__ __launch_bounds__(256) void k_scatter(const int* __restrict__ src,
                                                 const int* __restrict__ dst,
                                                 const float* __restrict__ ef,
                                                 const int* __restrict__ rp_in,
                                                 const float* __restrict__ dins,
                                                 int* __restrict__ cur_in,
                                                 int2* __restrict__ ndcsr,
                                                 float4* __restrict__ ef4,
                                                 float* __restrict__ c) {
    int e = blockIdx.x * 256 + threadIdx.x;
    if (e >= NE) return;
    int s = src[e], d = dst[e];
    int pi = rp_in[d] + atomicAdd(&cur_in[d], 1);
    ndcsr[pi] = make_int2(s, d);
    const float* er = ef + (size_t)e * 11;
    ef4[(size_t)pi * 3 + 0] = make_float4(er[0], er[1], er[2], er[3]);
    ef4[(size_t)pi * 3 + 1] = make_float4(er[4], er[5], er[6], er[7]);
    ef4[(size_t)pi * 3 + 2] = make_float4(er[8], er[9], er[10], 0.f);
    atomicAdd(&c[s], dins[d]);   // c[s] = sum over out-edges of din_dst
}

// ---------- K4: conv1 via CSR gather + fused 4->11 matvec/relu; h1s padded to 12 ----------
__global__ __launch_bounds__(256) void k_conv1g(const float4* __restrict__ xs4,
                                                const int2* __restrict__ ndcsr,
                                                const int* __restrict__ rp_in,
                                                const float* __restrict__ dins,
                                                const float* __restrict__ douts,
                                                const float* __restrict__ W1,
                                                const float* __restrict__ b1,
                                                float4* __restrict__ h1s4) {
    int n = blockIdx.x * 256 + threadIdx.x;
    if (n >= NN) return;
    float din  = dins[n];
    float dout = douts[n];
    float4 a = xs4[n];  // self-loop term, pre-scaled by dout_n
    int beg = rp_in[n], end = rp_in[n + 1];
    for (int p = beg; p < end; p++) {
        float4 xs = xs4[ndcsr[p].x];
        a.x += xs.x; a.y += xs.y; a.z += xs.z; a.w += xs.w;
    }
    float y[12];
    #pragma unroll
    for (int j = 0; j < 11; j++) {
        float t2 = a.x * W1[0 * 11 + j] + a.y * W1[1 * 11 + j] +
                   a.z * W1[2 * 11 + j] + a.w * W1[3 * 11 + j];
        y[j] = fmaxf(fmaf(t2, din, b1[j]), 0.f) * dout;
    }
    y[11] = 0.f;
    h1s4[(size_t)n * 3 + 0] = make_float4(y[0], y[1], y[2],  y[3]);
    h1s4[(size_t)n * 3 + 1] = make_float4(y[4], y[5], y[6],  y[7]);
    h1s4[(size_t)n * 3 + 2] = make_float4(y[8], y[9], y[10], y[11]);
}

// ---------- K5: conv2 — edge-parallel gather into LDS tile, then 2-ch/thread reduce ----------
// t_pad accumulators are line-padded (stride 16 floats) to avoid same-line atomic serialization.
#define G2 98
__global__ __launch_bounds__(256) void k_conv2f(const float4* __restrict__ h1s4,
                                                const float4* __restrict__ ef4,
                                                const int2* __restrict__ ndcsr,
                                                const int* __restrict__ rp_in,
                                                const float* __restrict__ c,
                                                const float* __restrict__ dins,
                                                const float* __restrict__ douts,
                                                const float* __restrict__ W2,
                                                const float* __restrict__ b2,
                                                float* __restrict__ t_pad) {
    __shared__ float tile[G2 * 12];
    __shared__ float din_sh[G2], w_sh[G2];
    int tid = threadIdx.x;
    int n0 = blockIdx.x * G2;
    int nend = (n0 + G2 < NN) ? n0 + G2 : NN;
    for (int i = tid; i < G2 * 12; i += 256) tile[i] = 0.f;
    if (tid < G2) {
        int n = n0 + tid;
        if (n < NN) {
            float din = dins[n];
            din_sh[tid] = din;
            w_sh[tid]   = (c[n] + din) * douts[n] * (1.0f / NN);  // +din = self loop
        } else { din_sh[tid] = 0.f; w_sh[tid] = 0.f; }
    }
    __syncthreads();
    int pbeg = rp_in[n0], pend = rp_in[nend];
    for (int p = pbeg + tid; p < pend; p += 256) {
        int2 sd = ndcsr[p];
        float4 ha = h1s4[(size_t)sd.x * 3 + 0];
        float4 hb = h1s4[(size_t)sd.x * 3 + 1];
        float4 hc = h1s4[(size_t)sd.x * 3 + 2];
        float4 ea = ef4[(size_t)p * 3 + 0];
        float4 eb = ef4[(size_t)p * 3 + 1];
        float4 ec = ef4[(size_t)p * 3 + 2];
        float* row = &tile[(sd.y - n0) * 12];
        atomicAdd(&row[0],  ha.x * ea.x);
        atomicAdd(&row[1],  ha.y * ea.y);
        atomicAdd(&row[2],  ha.z * ea.z);
        atomicAdd(&row[3],  ha.w * ea.w);
        atomicAdd(&row[4],  hb.x * eb.x);
        atomicAdd(&row[5],  hb.y * eb.y);
        atomicAdd(&row[6],  hb.z * eb.z);
        atomicAdd(&row[7],  hb.w * eb.w);
        atomicAdd(&row[8],  hc.x * ec.x);
        atomicAdd(&row[9],  hc.y * ec.y);
        atomicAdd(&row[10], hc.z * ec.z);
    }
    __syncthreads();
    // phase 2: two channels per thread
    int ch0 = tid, ch1 = tid + 256;
    float w0[11], w1[11];
    #pragma unroll
    for (int j = 0; j < 11; j++) { w0[j] = W2[j * 512 + ch0]; w1[j] = W2[j * 512 + ch1]; }
    float b0 = b2[ch0], b1v = b2[ch1];
    float acc0 = 0.f, acc1 = 0.f;
    int cnt = nend - n0;
    for (int i = 0; i < cnt; i++) {
        const float4* trow = (const float4*)&tile[i * 12];
        float4 ta = trow[0], tb = trow[1], tc = trow[2];
        float din = din_sh[i], wn = w_sh[i];
        float dot0 = ta.x * w0[0] + ta.y * w0[1] + ta.z * w0[2] + ta.w * w0[3] +
                     tb.x * w0[4] + tb.y * w0[5] + tb.z * w0[6] + tb.w * w0[7] +
                     tc.x * w0[8] + tc.y * w0[9] + tc.z * w0[10];
        float dot1 = ta.x * w1[0] + ta.y * w1[1] + ta.z * w1[2] + ta.w * w1[3] +
                     tb.x * w1[4] + tb.y * w1[5] + tb.z * w1[6] + tb.w * w1[7] +
                     tc.x * w1[8] + tc.y * w1[9] + tc.z * w1[10];
        acc0 = fmaf(wn, fmaxf(fmaf(dot0, din, b0),  0.f), acc0);
        acc1 = fmaf(wn, fmaxf(fmaf(dot1, din, b1v), 0.f), acc1);
    }
    atomicAdd(&t_pad[ch0 * 16], acc0);
    atomicAdd(&t_pad[ch1 * 16], acc1);
}

// ---------- K6: g = t @ W3 + b3  (512x1024 matvec, k-split 32 ways, padded acc) ----------
__global__ __launch_bounds__(256) void k_g(const float* __restrict__ t_pad,
                                           const float* __restrict__ W3,
                                           const float* __restrict__ b3,
                                           float* __restrict__ g_pad) {
    int b = blockIdx.x;          // 128 = 4 oc x 32 kc
    int oc = b & 3, kc = b >> 2;
    int o = oc * 256 + threadIdx.x;
    int k0 = kc * 16;
    __shared__ float ts[16];
    if (threadIdx.x < 16) ts[threadIdx.x] = t_pad[(k0 + threadIdx.x) * 16];
    __syncthreads();
    float acc = (kc == 0) ? b3[o] : 0.f;
    #pragma unroll
    for (int k = 0; k < 16; k++) acc = fmaf(ts[k], W3[(size_t)(k0 + k) * 1024 + o], acc);
    atomicAdd(&g_pad[o * 16], acc);
}

// ---------- K7: head layer-1 partial matvecs (bias/relu deferred, padded acc) ----------
// grid 512 = oc(16) x kc(32); outputs 0..2047 -> hv_pad, 2048..4095 -> ha_pad
__global__ __launch_bounds__(256) void k_heads1(const float* __restrict__ g_pad,
                                                const float* __restrict__ Wv1,
                                                const float* __restrict__ Wa1,
                                                float* __restrict__ hv_pad,
                                                float* __restrict__ ha_pad) {
    int b = blockIdx.x;
    int oc = b >> 5, kc = b & 31;
    int idx = oc * 256 + threadIdx.x;  // 0..4095
    int k0 = kc * 32;
    __shared__ float gs[32];
    if (threadIdx.x < 32) gs[threadIdx.x] = g_pad[(k0 + threadIdx.x) * 16];
    __syncthreads();
    const float* W; float* outp; int o;
    if (idx < 2048) { W = Wv1; outp = hv_pad; o = idx; }
    else            { W = Wa1; outp = ha_pad; o = idx - 2048; }
    float acc = 0.f;
    #pragma unroll 8
    for (int k = 0; k < 32; k++) acc = fmaf(gs[k], W[(size_t)(k0 + k) * 2048 + o], acc);
    atomicAdd(&outp[o * 16], acc);
}

// ---------- K8: head layer-2: a partials (256 blocks, padded acc) + v (1 block) ----------
__global__ __launch_bounds__(256) void k_heads2(const float* __restrict__ hv_pad,
                                                const float* __restrict__ bv1,
                                                const float* __restrict__ ha_pad,
                                                const float* __restrict__ ba1,
                                                const float* __restrict__ Wv2,
                                                const float* __restrict__ bv2,
                                                const float* __restrict__ Wa2,
                                                float* __restrict__ a_pad,
                                                float* __restrict__ v) {
    int b = blockIdx.x;
    int tid = threadIdx.x;
    if (b < 256) {
        int oc = b >> 6, kc = b & 63;   // oc 0..3, kc 0..63
        int k0 = kc * 32;
        __shared__ float hs[32];
        if (tid < 32) hs[tid] = fmaxf(ha_pad[(k0 + tid) * 16] + ba1[k0 + tid], 0.f);
        __syncthreads();
        int o = oc * 256 + tid;  // 0..1023
        if (o < 1000) {
            float acc = 0.f;
            #pragma unroll 8
            for (int k = 0; k < 32; k++)
                acc = fmaf(hs[k], Wa2[(size_t)(k0 + k) * 1000 + o], acc);
            atomicAdd(&a_pad[o * 16], acc);
        }
    } else {
        __shared__ float red[256];
        float acc = 0.f;
        for (int k = tid; k < 2048; k += 256)
            acc = fmaf(fmaxf(hv_pad[k * 16] + bv1[k], 0.f), Wv2[k], acc);
        red[tid] = acc;
        __syncthreads();
        for (int s = 128; s >= 1; s >>= 1) {
            if (tid < s) red[tid] += red[tid + s];
            __syncthreads();
        }
        if (tid == 0) *v = red[0] + bv2[0];
    }
}

// ---------- K9: final: out = v + (a - mean(a)) ----------
__global__ __launch_bounds__(1024) void k_final(const float* __restrict__ a_pad,
                                                const float* __restrict__ ba2,
                                                const float* __restrict__ vptr,
                                                float* __restrict__ out) {
    __shared__ float red[1024];
    int tid = threadIdx.x;
    float ai = (tid < 1000) ? a_pad[tid * 16] + ba2[tid] : 0.f;
    red[tid] = ai;
    __syncthreads();
    for (int s = 512; s >= 1; s >>= 1) {
        if (tid < s) red[tid] += red[tid + s];
        __syncthreads();
    }
    float amean = red[0] * (1.0f / 1000.0f);
    if (tid < 1000) out[tid] = vptr[0] + ai - amean;
}

extern "C" void kernel_launch(void* const* d_in, const int* in_sizes, int n_in,
                              void* d_out, int out_size, void* d_ws, size_t ws_size,
                              hipStream_t stream) {
    const float* x   = (const float*)d_in[0];
    const float* ef  = (const float*)d_in[1];
    const float* W1  = (const float*)d_in[2];
    const float* b1  = (const float*)d_in[3];
    const float* W2  = (const float*)d_in[4];
    const float* b2  = (const float*)d_in[5];
    const float* W3  = (const float*)d_in[6];
    const float* b3  = (const float*)d_in[7];
    const float* Wv1 = (const float*)d_in[8];
    const float* bv1 = (const float*)d_in[9];
    const float* Wv2 = (const float*)d_in[10];
    const float* bv2 = (const float*)d_in[11];
    const float* Wa1 = (const float*)d_in[12];
    const float* ba1 = (const float*)d_in[13];
    const float* Wa2 = (const float*)d_in[14];
    const float* ba2 = (const float*)d_in[15];
    const int*   src = (const int*)d_in[16];
    const int*   dst = (const int*)d_in[17];
    float* out = (float*)d_out;

    char* ws = (char*)d_ws;
    size_t off = 0;
    auto alloc = [&](size_t bytes) -> void* {
        void* p = ws + off;
        off = (off + bytes + 255) & ~(size_t)255;
        return p;
    };
    // --- zeroed region (accumulators) ---
    int*   deg_out = (int*)  alloc(NN * 4);
    int*   deg_in  = (int*)  alloc(NN * 4);
    int*   cur_in  = (int*)  alloc(NN * 4);
    float* c       = (float*)alloc(NN * 4);
    float* t_pad   = (float*)alloc(512 * 16 * 4);
    float* g_pad   = (float*)alloc(1024 * 16 * 4);
    float* hv_pad  = (float*)alloc(2048 * 16 * 4);
    float* ha_pad  = (float*)alloc(2048 * 16 * 4);
    float* a_pad   = (float*)alloc(1024 * 16 * 4);
    size_t zero_bytes = off;
    // --- non-zeroed scratch ---
    int*    bsum_in  = (int*)   alloc(NB * 4);
    int*    rp_in    = (int*)   alloc((NN + 1) * 4);
    float*  dins     = (float*) alloc(NN * 4);
    float*  douts    = (float*) alloc(NN * 4);
    float4* xs4      = (float4*)alloc((size_t)NN * 16);
    int2*   ndcsr    = (int2*)  alloc((size_t)NE * 8);
    float4* ef4      = (float4*)alloc((size_t)NE * 48);
    float4* h1s4     = (float4*)alloc((size_t)NN * 48);
    float*  v        = (float*) alloc(256);

    hipMemsetAsync(d_ws, 0, zero_bytes, stream);

    k_deg<<<(NE + 255) / 256, 256, 0, stream>>>(src, dst, deg_out, deg_in);
    k_bsum<<<NB, 256, 0, stream>>>(deg_in, bsum_in);
    k_rowptr<<<NB, 256, 0, stream>>>(deg_in, deg_out, bsum_in, x, rp_in, dins, douts, xs4);
    k_scatter<<<(NE + 255) / 256, 256, 0, stream>>>(src, dst, ef, rp_in, dins,
                                                    cur_in, ndcsr, ef4, c);
    k_conv1g<<<(NN + 255) / 256, 256, 0, stream>>>(xs4, ndcsr, rp_in, dins, douts,
                                                   W1, b1, h1s4);
    k_conv2f<<<(NN + G2 - 1) / G2, 256, 0, stream>>>(h1s4, ef4, ndcsr, rp_in, c,
                                                     dins, douts, W2, b2, t_pad);
    k_g<<<128, 256, 0, stream>>>(t_pad, W3, b3, g_pad);
    k_heads1<<<512, 256, 0, stream>>>(g_pad, Wv1, Wa1, hv_pad, ha_pad);
    k_heads2<<<257, 256, 0, stream>>>(hv_pad, bv1, ha_pad, ba1, Wv2, bv2, Wa2, a_pad, v);
    k_final<<<1, 1024, 0, stream>>>(a_pad, ba2, v, out);
}